// Round 13
// baseline (388.369 us; speedup 1.0000x reference)
//
#include <hip/hip_runtime.h>
#include <stdint.h>

typedef __attribute__((ext_vector_type(8))) short short8;    // 8 bf16 = 16B
typedef __attribute__((ext_vector_type(4))) short short4v;
typedef __attribute__((ext_vector_type(4))) float f32x4;
typedef __attribute__((ext_vector_type(2))) uint32_t u32x2;

#define DEV static __device__ __forceinline__

DEV short f2bf(float f) {
  union { float f; uint32_t u; } v; v.f = f;
  uint32_t r = (v.u + 0x7fffu + ((v.u >> 16) & 1u)) >> 16;
  return (short)(uint16_t)r;
}
DEV float bf2f(short s) {
  union { uint32_t u; float f; } v; v.u = ((uint32_t)(uint16_t)s) << 16;
  return v.f;
}
DEV int imin(int a, int b) { return a < b ? a : b; }
// v_cvt_pk_bf16_f32: D.lo = bf16(S0), D.hi = bf16(S1)  [T12 recipe order]
DEV uint32_t cvtpk(float lo, float hi) {
  uint32_t r;
  asm volatile("v_cvt_pk_bf16_f32 %0, %1, %2" : "=v"(r) : "v"(lo), "v"(hi));
  return r;
}
// bijective XCD chunking (m204): consecutive remapped IDs share an XCD
DEV int xcd_swz(int bid, int nwg) {
  int q8 = nwg >> 3, r8 = nwg & 7;
  int xcd = bid & 7, lin = bid >> 3;
  return (xcd < r8 ? xcd * (q8 + 1) : r8 * (q8 + 1) + (xcd - r8) * q8) + lin;
}

// B=4, S=2048, D=640, H=8, d=80, C=768, A=16

// ---------------------------------------------------------------------------
// 0. dtype detector
// ---------------------------------------------------------------------------
__global__ void k_detect(const uint32_t* __restrict__ src, int* __restrict__ flag) {
  __shared__ int cnt;
  if (threadIdx.x == 0) cnt = 0;
  __syncthreads();
  uint32_t u = src[threadIdx.x];
  int e = (int)((u >> 7) & 0xffu);
  if (e >= 110 && e <= 135) atomicAdd(&cnt, 1);
  __syncthreads();
  if (threadIdx.x == 0) *flag = (cnt > 128) ? 1 : 0;
}

// ---------------------------------------------------------------------------
// 1. fused converters
// ---------------------------------------------------------------------------
__global__ void k_conv_vec(const void* __restrict__ s1, short* __restrict__ d1, int n1,
                           const void* __restrict__ s2, short* __restrict__ d2, int n2,
                           const int* __restrict__ flag) {
  int i = blockIdx.x * 256 + threadIdx.x;
  const void* src; short* dst;
  if (i < n1) { src = s1; dst = d1; }
  else if (i < n1 + n2) { src = s2; dst = d2; i -= n1; }
  else return;
  if (*flag) {
    ((short4v*)dst)[i] = ((const short4v*)src)[i];
  } else {
    f32x4 v = ((const f32x4*)src)[i];
    short4v o;
    o[0] = f2bf(v[0]); o[1] = f2bf(v[1]); o[2] = f2bf(v[2]); o[3] = f2bf(v[3]);
    ((short4v*)dst)[i] = o;
  }
}

struct WDesc { const void* src; short* dst; int K, N, dstride, tile0; };
struct WTable { WDesc d[8]; };

__global__ void k_conv_w(WTable tb, const int* __restrict__ flag) {
  __shared__ float tile[32][33];
  int tid = blockIdx.x;
  int idx = 0;
#pragma unroll
  for (int i = 1; i < 8; i++) if (tid >= tb.d[i].tile0) idx = i;
  WDesc wd = tb.d[idx];
  int local = tid - wd.tile0;
  int ntiles = wd.N >> 5;
  int n0 = (local % ntiles) * 32, k0 = (local / ntiles) * 32;
  int tx = threadIdx.x, ty = threadIdx.y;  // 32 x 8
  int isbf = *flag;
#pragma unroll
  for (int i = 0; i < 4; i++) {
    int r = k0 + ty + i * 8, c = n0 + tx;
    float v = 0.f;
    if (r < wd.K && c < wd.N)
      v = isbf ? bf2f(((const short*)wd.src)[(size_t)r * wd.N + c])
               : ((const float*)wd.src)[(size_t)r * wd.N + c];
    tile[ty + i * 8][tx] = v;
  }
  __syncthreads();
#pragma unroll
  for (int i = 0; i < 4; i++) {
    int n = n0 + ty + i * 8, k = k0 + tx;
    if (n < wd.N && k < wd.K) wd.dst[(size_t)n * wd.dstride + k] = f2bf(tile[tx][ty + i * 8]);
  }
}

__global__ void k_conv_bias(const void* b1, const void* b2, const void* b3, const void* tp,
                            float* B1, float* B2, float* B3, float* T,
                            const int* __restrict__ flag) {
  int i = blockIdx.x * 256 + threadIdx.x;
  int isbf = *flag;
  const void* s; float* d; int j;
  if (i < 320) { s = b1; d = B1; j = i; }
  else if (i < 960) { s = b2; d = B2; j = i - 320; }
  else if (i < 1600) { s = b3; d = B3; j = i - 960; }
  else if (i == 1600) { s = tp; d = T; j = 0; }
  else return;
  d[j] = isbf ? bf2f(((const short*)s)[j]) : ((const float*)s)[j];
}

// ---------------------------------------------------------------------------
// 2. MFMA GEMM: 128x128 tile, BK=64, global_load_lds width-16, XCD-chunked.
//    EPI 0 + vtout: V-region cols (>=1280) go to VT (pi-permuted) instead of C.
// ---------------------------------------------------------------------------
template <int EPI>
__global__ __launch_bounds__(256) void k_gemm_bt(
    const short* __restrict__ A, const short* __restrict__ Wt, void* __restrict__ Cout,
    int M, int N, int K, int nbx,
    const float* __restrict__ bias, const short* __restrict__ x1,
    const short* __restrict__ x2, const short* __restrict__ res,
    short* __restrict__ vtout) {
  __shared__ __align__(16) short As[128 * 64];
  __shared__ __align__(16) short Bs[128 * 64];
  const int t = threadIdx.x;
  const int w = t >> 6, ln = t & 63;
  const int wm = w >> 1, wn = w & 1;
  const int swz = xcd_swz(blockIdx.x, gridDim.x);
  const int m0 = (swz / nbx) * 128, n0 = (swz % nbx) * 128;
  const int lrow = ln & 15, lg = ln >> 4;

  f32x4 acc[4][4];
#pragma unroll
  for (int i = 0; i < 4; i++)
#pragma unroll
    for (int j = 0; j < 4; j++) acc[i][j] = (f32x4){0.f, 0.f, 0.f, 0.f};

  for (int k0 = 0; k0 < K; k0 += 64) {
    __syncthreads();
#pragma unroll
    for (int c = 0; c < 4; c++) {
      int cc = c * 256 + t;
      int r = cc >> 3, col = (cc & 7) * 8;
      int ra = imin(m0 + r, M - 1);
      int rb = imin(n0 + r, N - 1);
      __builtin_amdgcn_global_load_lds(
          (const __attribute__((address_space(1))) void*)(A + (size_t)ra * K + k0 + col),
          (__attribute__((address_space(3))) void*)&As[(c * 256 + w * 64) * 8],
          16, 0, 0);
      __builtin_amdgcn_global_load_lds(
          (const __attribute__((address_space(1))) void*)(Wt + (size_t)rb * K + k0 + col),
          (__attribute__((address_space(3))) void*)&Bs[(c * 256 + w * 64) * 8],
          16, 0, 0);
    }
    __syncthreads();
    short8 af[4][2], bfr[4][2];
#pragma unroll
    for (int i = 0; i < 4; i++)
#pragma unroll
      for (int kk = 0; kk < 2; kk++) {
        af[i][kk] = *(const short8*)&As[(wm * 64 + i * 16 + lrow) * 64 + lg * 8 + kk * 32];
        bfr[i][kk] = *(const short8*)&Bs[(wn * 64 + i * 16 + lrow) * 64 + lg * 8 + kk * 32];
      }
    __builtin_amdgcn_s_setprio(1);
#pragma unroll
    for (int kk = 0; kk < 2; kk++)
#pragma unroll
      for (int i = 0; i < 4; i++)
#pragma unroll
        for (int j = 0; j < 4; j++)
          acc[i][j] = __builtin_amdgcn_mfma_f32_16x16x32_bf16(af[i][kk], bfr[j][kk], acc[i][j], 0, 0, 0);
    __builtin_amdgcn_s_setprio(0);
  }

  const int rb0 = m0 + wm * 64 + lg * 4;
#pragma unroll
  for (int i = 0; i < 4; i++) {
#pragma unroll
    for (int j = 0; j < 4; j++) {
      int col = n0 + wn * 64 + j * 16 + lrow;
      if (col >= N) continue;
#pragma unroll
      for (int r = 0; r < 4; r++) {
        int row = rb0 + i * 16 + r;
        if (row >= M) continue;
        float v = acc[i][j][r];
        size_t off = (size_t)row * N + col;
        if (EPI == 0) {
          if (vtout && col >= 1280) {
            // write V directly into VT [bh][d][S] with pi permutation
            int hh = (col - 1280) / 80, dd = (col - 1280) % 80;
            int bq = row >> 11, srow = row & 2047;
            int q = (srow & ~63) | (((srow & 15) << 2) | ((srow >> 4) & 3));
            vtout[((size_t)((bq << 3) + hh) * 80 + dd) * 2048 + q] = f2bf(v);
          } else {
            ((short*)Cout)[off] = f2bf(v);
          }
        } else if (EPI == 1) {
          float x = v + bias[col];
          ((short*)Cout)[off] = f2bf(x / (1.f + __expf(-x)));
        } else if (EPI == 2) {
          float g = 1.f / (1.f + __expf(-(v + bias[col])));
          ((short*)Cout)[off] = f2bf(bf2f(x1[off]) + g * bf2f(x2[off]));
        } else {
          ((float*)Cout)[off] = v + bias[col] + bf2f(res[off]);
        }
      }
    }
  }
}

// ---------------------------------------------------------------------------
// 4. Flash attention (r3-verified structure + r12 VALU cuts + cvt_pk P-pack)
// ---------------------------------------------------------------------------
__global__ __launch_bounds__(256) void k_attn(const short* __restrict__ qkv,
                                              const short* __restrict__ vt,
                                              short* __restrict__ outp) {
  __shared__ __align__(16) short Ks[64 * 104];
  __shared__ __align__(16) char Vs[80 * 128];
  __shared__ __align__(16) char Ps[4][2048];

  // 1024 blocks, 128/XCD -> 32 consecutive swz share bh (K/V panels, 2.6MB/XCD)
  const int swzb = xcd_swz(blockIdx.x, 1024);
  const int qt = swzb & 31, bh = swzb >> 5;
  const int b = bh >> 3, h = bh & 7;
  const int t = threadIdx.x, w = t >> 6, ln = t & 63;
  const int lg = ln >> 4, lr = ln & 15;
  const float sc2 = 0.111803398875f * 1.4426950408889634f;  // scale * log2(e)
  const float SHIFT2 = 32.0f;  // fixed softmax shift (log2 domain)

  short8 qfrag[3];
  {
    const short* qrow = qkv + (size_t)(b * 2048 + qt * 64 + w * 16 + lr) * 1920 + h * 80;
#pragma unroll
    for (int ks = 0; ks < 3; ks++) {
      int off = ks * 32 + lg * 8;
      short8 v = {0, 0, 0, 0, 0, 0, 0, 0};
      if (off < 80) v = *(const short8*)(qrow + off);
      qfrag[ks] = v;
    }
  }

  const short* kbase = qkv + (size_t)b * 2048 * 1920 + 640 + h * 80;
  const short* vbase = vt + (size_t)bh * 80 * 2048;

  int kr[3], kb[3], vr[3], vb[3];
#pragma unroll
  for (int i = 0; i < 3; i++) {
    int c = t + i * 256;
    kr[i] = c / 12; kb[i] = c % 12;
    vr[i] = c >> 3; vb[i] = c & 7;
  }

  short8 kreg[3], vreg[3];
#pragma unroll
  for (int i = 0; i < 3; i++) { kreg[i] = (short8){0,0,0,0,0,0,0,0}; vreg[i] = kreg[i]; }

#pragma unroll
  for (int i = 0; i < 3; i++) {
    if (kb[i] < 10) kreg[i] = *(const short8*)(kbase + (size_t)kr[i] * 1920 + kb[i] * 8);
    if (i < 2 || t < 128) vreg[i] = *(const short8*)(vbase + (size_t)vr[i] * 2048 + vb[i] * 8);
  }

  f32x4 oacc[5];
#pragma unroll
  for (int f = 0; f < 5; f++) oacc[f] = (f32x4){0.f, 0.f, 0.f, 0.f};
  float psacc[4] = {0.f, 0.f, 0.f, 0.f};  // per-lane partial row sums

  for (int kt = 0; kt < 32; kt++) {
    __syncthreads();
#pragma unroll
    for (int i = 0; i < 3; i++)
      *(short8*)&Ks[kr[i] * 104 + kb[i] * 8] = kreg[i];
#pragma unroll
    for (int i = 0; i < 3; i++) {
      if (i < 2 || t < 128) {
        int dst = (vr[i] * 128 + vb[i] * 16) ^ ((vr[i] & 7) << 4);
        *(short8*)&Vs[dst] = vreg[i];
      }
    }
    __syncthreads();

    if (kt < 31) {
      const short* kb2 = kbase + (size_t)(kt + 1) * 64 * 1920;
      const short* vb2 = vbase + (size_t)(kt + 1) * 64;
#pragma unroll
      for (int i = 0; i < 3; i++) {
        if (kb[i] < 10) kreg[i] = *(const short8*)(kb2 + (size_t)kr[i] * 1920 + kb[i] * 8);
        if (i < 2 || t < 128) vreg[i] = *(const short8*)(vb2 + (size_t)vr[i] * 2048 + vb[i] * 8);
      }
    }

    f32x4 sf[4];
#pragma unroll
    for (int j = 0; j < 4; j++) sf[j] = (f32x4){0.f, 0.f, 0.f, 0.f};
    __builtin_amdgcn_s_setprio(1);
#pragma unroll
    for (int ks = 0; ks < 3; ks++) {
#pragma unroll
      for (int j = 0; j < 4; j++) {
        short8 bk = *(const short8*)&Ks[(j * 16 + lr) * 104 + ks * 32 + lg * 8];
        sf[j] = __builtin_amdgcn_mfma_f32_16x16x32_bf16(qfrag[ks], bk, sf[j], 0, 0, 0);
      }
    }
    __builtin_amdgcn_s_setprio(0);

    // fixed-shift softmax; P packed with v_cvt_pk_bf16_f32 (lo = even col)
    char* Pw = Ps[w];
#pragma unroll
    for (int r = 0; r < 4; r++) {
      int row = lg * 4 + r;
      float p0 = exp2f(sf[0][r] * sc2 - SHIFT2);
      float p1 = exp2f(sf[1][r] * sc2 - SHIFT2);
      float p2 = exp2f(sf[2][r] * sc2 - SHIFT2);
      float p3 = exp2f(sf[3][r] * sc2 - SHIFT2);
      psacc[r] += (p0 + p1) + (p2 + p3);
      u32x2 pk;
      pk[0] = cvtpk(p0, p1);
      pk[1] = cvtpk(p2, p3);
      int addr = (row * 128 + lr * 8) ^ ((row & 7) << 4);
      *(u32x2*)&Pw[addr] = pk;
    }

    __builtin_amdgcn_s_setprio(1);
#pragma unroll
    for (int ks = 0; ks < 2; ks++) {
      short8 ap = *(const short8*)&Pw[(lr * 128 + ks * 64 + lg * 16) ^ ((lr & 7) << 4)];
#pragma unroll
      for (int f = 0; f < 5; f++) {
        int vrow = f * 16 + lr;
        short8 bv = *(const short8*)&Vs[(vrow * 128 + ks * 64 + lg * 16) ^ ((vrow & 7) << 4)];
        oacc[f] = __builtin_amdgcn_mfma_f32_16x16x32_bf16(ap, bv, oacc[f], 0, 0, 0);
      }
    }
    __builtin_amdgcn_s_setprio(0);
  }

  // deferred row-sum reduce (once, not per tile)
  float lrowv[4];
#pragma unroll
  for (int r = 0; r < 4; r++) {
    float sum = psacc[r];
#pragma unroll
    for (int off = 8; off >= 1; off >>= 1) sum += __shfl_xor(sum, off, 64);
    lrowv[r] = sum;
  }

#pragma unroll
  for (int f = 0; f < 5; f++) {
#pragma unroll
    for (int r = 0; r < 4; r++) {
      int q = qt * 64 + w * 16 + lg * 4 + r;
      float o = oacc[f][r] / lrowv[r];
      outp[(size_t)(b * 2048 + q) * 640 + h * 80 + f * 16 + lr] = f2bf(o);
    }
  }
}

// ---------------------------------------------------------------------------
// 5. AU cross-attention (A=16 kv); aukv = [64][1280] (K | V)
// ---------------------------------------------------------------------------
__global__ __launch_bounds__(256) void k_au_attn(const short* __restrict__ qkv,
                                                 const short* __restrict__ aukv,
                                                 const float* __restrict__ temp,
                                                 short* __restrict__ auhs) {
  __shared__ __align__(16) short aK[16 * 640];
  __shared__ __align__(16) short aV[16 * 640];
  const int b = blockIdx.y;
  const int t = threadIdx.x;
  for (int c = t; c < 2560; c += 256) {
    int arr = c / 1280, cc = c - arr * 1280;
    int r = cc / 80, blk = cc % 80;
    const short* s = aukv + (size_t)(b * 16 + r) * 1280 + arr * 640 + blk * 8;
    short* d = (arr ? aV : aK) + r * 640 + blk * 8;
    *(short8*)d = *(const short8*)s;
  }
  __syncthreads();
  const int sl = t & 31, h = t >> 5;
  const int s = blockIdx.x * 32 + sl;
  const float alpha = 0.111803398875f * temp[0];
  const float LOG2E = 1.4426950408889634f;

  float qf[80];
  {
    const short* q = qkv + (size_t)(b * 2048 + s) * 1920 + h * 80;
#pragma unroll
    for (int c = 0; c < 10; c++) {
      short8 v = *(const short8*)(q + c * 8);
#pragma unroll
      for (int j = 0; j < 8; j++) qf[c * 8 + j] = bf2f(v[j]);
    }
  }
  float lgt[16];
#pragma unroll
  for (int a = 0; a < 16; a++) {
    const short* kr = &aK[a * 640 + h * 80];
    float acc = 0.f;
#pragma unroll
    for (int c = 0; c < 10; c++) {
      short8 v = *(const short8*)(kr + c * 8);
#pragma unroll
      for (int j = 0; j < 8; j++) acc += qf[c * 8 + j] * bf2f(v[j]);
    }
    lgt[a] = acc * alpha;
  }
  float m = lgt[0];
#pragma unroll
  for (int a = 1; a < 16; a++) m = fmaxf(m, lgt[a]);
  float se = 0.f;
#pragma unroll
  for (int a = 0; a < 16; a++) { lgt[a] = exp2f((lgt[a] - m) * LOG2E); se += lgt[a]; }
  float inv = 1.f / se;

  float o[80];
#pragma unroll
  for (int i = 0; i < 80; i++) o[i] = 0.f;
#pragma unroll
  for (int a = 0; a < 16; a++) {
    float pa = lgt[a] * inv;
    const short* vr = &aV[a * 640 + h * 80];
#pragma unroll
    for (int c = 0; c < 10; c++) {
      short8 v = *(const short8*)(vr + c * 8);
#pragma unroll
      for (int j = 0; j < 8; j++) o[c * 8 + j] += pa * bf2f(v[j]);
    }
  }
  short* op = auhs + (size_t)(b * 2048 + s) * 640 + h * 80;
#pragma unroll
  for (int c = 0; c < 10; c++) {
    short8 v;
#pragma unroll
    for (int j = 0; j < 8; j++) v[j] = f2bf(o[c * 8 + j]);
    *(short8*)(op + c * 8) = v;
  }
}

// ---------------------------------------------------------------------------
// Orchestration
// ---------------------------------------------------------------------------
extern "C" void kernel_launch(void* const* d_in, const int* in_sizes, int n_in,
                              void* d_out, int out_size, void* d_ws, size_t ws_size,
                              hipStream_t stream) {
  (void)in_sizes; (void)n_in; (void)out_size; (void)ws_size;

  const void* hidden = d_in[0];
  const void* auemb  = d_in[1];

  char* ws = (char*)d_ws;
  int* FLAG   = (int*)(ws + 0);
  float* BG1  = (float*)(ws + 1024);
  float* BG2  = (float*)(ws + 4096);
  float* BOUT = (float*)(ws + 8192);
  float* TEMP = (float*)(ws + 12288);

  size_t o = 16384;
  short* HSB = (short*)(ws + o);    o += 10485760;  // [8192][640]
  short* AUB = (short*)(ws + o);    o += 98304;     // [64][768]
  short* WQKVT = (short*)(ws + o);  o += 2457600;   // [1920][640]
  short* WAKVT = (short*)(ws + o);  o += 1966080;   // [1280][768]
  short* WG1T = (short*)(ws + o);   o += 409600;    // [320][640]
  short* WG2T = (short*)(ws + o);   o += 409600;    // [640][320]
  short* WOUTT = (short*)(ws + o);  o += 819200;    // [640][640]
  short* QKV = (short*)(ws + o);    o += 31457280;  // [8192][1920] (V region unused)
  short* VT = (short*)(ws + o);     o += 10485760;  // [32][80][2048] pi-permuted
  short* AUKV = (short*)(ws + o);   o += 163840;    // [64][1280]
  short* HSATTN = (short*)(ws + o); o += 10485760;  // [8192][640]
  short* AUHS = (short*)(ws + o);   o += 10485760;  // [8192][640]
  short* G1 = QKV;                                   // reuse: [8192][320]
  short* HSMIX = QKV + 5242880;                      // reuse: [8192][640]

  k_detect<<<1, 256, 0, stream>>>((const uint32_t*)hidden, FLAG);

  k_conv_vec<<<5168, 256, 0, stream>>>(hidden, HSB, 1310720, auemb, AUB, 12288, FLAG);

  WTable tb;
  tb.d[0] = { d_in[2],  WQKVT,              640, 640, 640, 0    };  // w_q
  tb.d[1] = { d_in[3],  WQKVT + 409600,     640, 640, 640, 400  };  // w_k
  tb.d[2] = { d_in[4],  WQKVT + 819200,     640, 640, 640, 800  };  // w_v
  tb.d[3] = { d_in[5],  WAKVT,              768, 640, 768, 1200 };  // w_ak
  tb.d[4] = { d_in[6],  WAKVT + 640 * 768,  768, 640, 768, 1680 };  // w_av
  tb.d[5] = { d_in[7],  WG1T,               640, 320, 640, 2160 };  // w_g1
  tb.d[6] = { d_in[9],  WG2T,               320, 640, 320, 2360 };  // w_g2
  tb.d[7] = { d_in[11], WOUTT,              640, 640, 640, 2560 };  // w_out
  k_conv_w<<<2960, dim3(32, 8), 0, stream>>>(tb, FLAG);
  k_conv_bias<<<7, 256, 0, stream>>>(d_in[8], d_in[10], d_in[12], d_in[13],
                                     BG1, BG2, BOUT, TEMP, FLAG);

  // QKV projection: [8192,640] @ [640,1920]; V cols stream into VT (pi-permuted)
  k_gemm_bt<0><<<960, 256, 0, stream>>>(HSB, WQKVT, QKV, 8192, 1920, 640, 15,
                                        nullptr, nullptr, nullptr, nullptr, VT);
  // au_k | au_v fused: [64,768] @ [768,1280]
  k_gemm_bt<0><<<10, 256, 0, stream>>>(AUB, WAKVT, AUKV, 64, 1280, 768, 10,
                                       nullptr, nullptr, nullptr, nullptr, nullptr);

  k_attn<<<1024, 256, 0, stream>>>(QKV, VT, HSATTN);
  k_au_attn<<<dim3(64, 4), 256, 0, stream>>>(QKV, AUKV, TEMP, AUHS);

  // gate MLP
  k_gemm_bt<1><<<192, 256, 0, stream>>>(AUHS, WG1T, G1, 8192, 320, 640, 3,
                                        BG1, nullptr, nullptr, nullptr, nullptr);
  k_gemm_bt<2><<<320, 256, 0, stream>>>(G1, WG2T, HSMIX, 8192, 640, 320, 5,
                                        BG2, HSATTN, AUHS, nullptr, nullptr);
  // final out (float32)
  k_gemm_bt<3><<<320, 256, 0, stream>>>(HSMIX, WOUTT, d_out, 8192, 640, 640, 5,
                                        BOUT, nullptr, nullptr, HSB, nullptr);
}

// Round 14
// 344.572 us; speedup vs baseline: 1.1271x; 1.1271x over previous
//
#include <hip/hip_runtime.h>
#include <stdint.h>

typedef __attribute__((ext_vector_type(8))) short short8;    // 8 bf16 = 16B
typedef __attribute__((ext_vector_type(4))) short short4v;
typedef __attribute__((ext_vector_type(4))) float f32x4;

#define DEV static __device__ __forceinline__

DEV short f2bf(float f) {
  union { float f; uint32_t u; } v; v.f = f;
  uint32_t r = (v.u + 0x7fffu + ((v.u >> 16) & 1u)) >> 16;
  return (short)(uint16_t)r;
}
DEV float bf2f(short s) {
  union { uint32_t u; float f; } v; v.u = ((uint32_t)(uint16_t)s) << 16;
  return v.f;
}
DEV int imin(int a, int b) { return a < b ? a : b; }
// bijective XCD chunking (m204): consecutive remapped IDs share an XCD
DEV int xcd_swz(int bid, int nwg) {
  int q8 = nwg >> 3, r8 = nwg & 7;
  int xcd = bid & 7, lin = bid >> 3;
  return (xcd < r8 ? xcd * (q8 + 1) : r8 * (q8 + 1) + (xcd - r8) * q8) + lin;
}

// B=4, S=2048, D=640, H=8, d=80, C=768, A=16

// ---------------------------------------------------------------------------
// 0. dtype detector
// ---------------------------------------------------------------------------
__global__ void k_detect(const uint32_t* __restrict__ src, int* __restrict__ flag) {
  __shared__ int cnt;
  if (threadIdx.x == 0) cnt = 0;
  __syncthreads();
  uint32_t u = src[threadIdx.x];
  int e = (int)((u >> 7) & 0xffu);
  if (e >= 110 && e <= 135) atomicAdd(&cnt, 1);
  __syncthreads();
  if (threadIdx.x == 0) *flag = (cnt > 128) ? 1 : 0;
}

// ---------------------------------------------------------------------------
// 1. fused converters
// ---------------------------------------------------------------------------
__global__ void k_conv_vec(const void* __restrict__ s1, short* __restrict__ d1, int n1,
                           const void* __restrict__ s2, short* __restrict__ d2, int n2,
                           const int* __restrict__ flag) {
  int i = blockIdx.x * 256 + threadIdx.x;
  const void* src; short* dst;
  if (i < n1) { src = s1; dst = d1; }
  else if (i < n1 + n2) { src = s2; dst = d2; i -= n1; }
  else return;
  if (*flag) {
    ((short4v*)dst)[i] = ((const short4v*)src)[i];
  } else {
    f32x4 v = ((const f32x4*)src)[i];
    short4v o;
    o[0] = f2bf(v[0]); o[1] = f2bf(v[1]); o[2] = f2bf(v[2]); o[3] = f2bf(v[3]);
    ((short4v*)dst)[i] = o;
  }
}

struct WDesc { const void* src; short* dst; int K, N, dstride, tile0; };
struct WTable { WDesc d[8]; };

__global__ void k_conv_w(WTable tb, const int* __restrict__ flag) {
  __shared__ float tile[32][33];
  int tid = blockIdx.x;
  int idx = 0;
#pragma unroll
  for (int i = 1; i < 8; i++) if (tid >= tb.d[i].tile0) idx = i;
  WDesc wd = tb.d[idx];
  int local = tid - wd.tile0;
  int ntiles = wd.N >> 5;
  int n0 = (local % ntiles) * 32, k0 = (local / ntiles) * 32;
  int tx = threadIdx.x, ty = threadIdx.y;  // 32 x 8
  int isbf = *flag;
#pragma unroll
  for (int i = 0; i < 4; i++) {
    int r = k0 + ty + i * 8, c = n0 + tx;
    float v = 0.f;
    if (r < wd.K && c < wd.N)
      v = isbf ? bf2f(((const short*)wd.src)[(size_t)r * wd.N + c])
               : ((const float*)wd.src)[(size_t)r * wd.N + c];
    tile[ty + i * 8][tx] = v;
  }
  __syncthreads();
#pragma unroll
  for (int i = 0; i < 4; i++) {
    int n = n0 + ty + i * 8, k = k0 + tx;
    if (n < wd.N && k < wd.K) wd.dst[(size_t)n * wd.dstride + k] = f2bf(tile[tx][ty + i * 8]);
  }
}

__global__ void k_conv_bias(const void* b1, const void* b2, const void* b3, const void* tp,
                            float* B1, float* B2, float* B3, float* T,
                            const int* __restrict__ flag) {
  int i = blockIdx.x * 256 + threadIdx.x;
  int isbf = *flag;
  const void* s; float* d; int j;
  if (i < 320) { s = b1; d = B1; j = i; }
  else if (i < 960) { s = b2; d = B2; j = i - 320; }
  else if (i < 1600) { s = b3; d = B3; j = i - 960; }
  else if (i == 1600) { s = tp; d = T; j = 0; }
  else return;
  d[j] = isbf ? bf2f(((const short*)s)[j]) : ((const float*)s)[j];
}

// ---------------------------------------------------------------------------
// 2. MFMA GEMM: 128x128 tile, BK=64, global_load_lds width-16, XCD-chunked
// ---------------------------------------------------------------------------
template <int EPI>
__global__ __launch_bounds__(256) void k_gemm_bt(
    const short* __restrict__ A, const short* __restrict__ Wt, void* __restrict__ Cout,
    int M, int N, int K, int nbx,
    const float* __restrict__ bias, const short* __restrict__ x1,
    const short* __restrict__ x2, const short* __restrict__ res) {
  __shared__ __align__(16) short As[128 * 64];
  __shared__ __align__(16) short Bs[128 * 64];
  const int t = threadIdx.x;
  const int w = t >> 6, ln = t & 63;
  const int wm = w >> 1, wn = w & 1;
  const int swz = xcd_swz(blockIdx.x, gridDim.x);
  const int m0 = (swz / nbx) * 128, n0 = (swz % nbx) * 128;
  const int lrow = ln & 15, lg = ln >> 4;

  f32x4 acc[4][4];
#pragma unroll
  for (int i = 0; i < 4; i++)
#pragma unroll
    for (int j = 0; j < 4; j++) acc[i][j] = (f32x4){0.f, 0.f, 0.f, 0.f};

  for (int k0 = 0; k0 < K; k0 += 64) {
    __syncthreads();
#pragma unroll
    for (int c = 0; c < 4; c++) {
      int cc = c * 256 + t;
      int r = cc >> 3, col = (cc & 7) * 8;
      int ra = imin(m0 + r, M - 1);
      int rb = imin(n0 + r, N - 1);
      __builtin_amdgcn_global_load_lds(
          (const __attribute__((address_space(1))) void*)(A + (size_t)ra * K + k0 + col),
          (__attribute__((address_space(3))) void*)&As[(c * 256 + w * 64) * 8],
          16, 0, 0);
      __builtin_amdgcn_global_load_lds(
          (const __attribute__((address_space(1))) void*)(Wt + (size_t)rb * K + k0 + col),
          (__attribute__((address_space(3))) void*)&Bs[(c * 256 + w * 64) * 8],
          16, 0, 0);
    }
    __syncthreads();
    short8 af[4][2], bfr[4][2];
#pragma unroll
    for (int i = 0; i < 4; i++)
#pragma unroll
      for (int kk = 0; kk < 2; kk++) {
        af[i][kk] = *(const short8*)&As[(wm * 64 + i * 16 + lrow) * 64 + lg * 8 + kk * 32];
        bfr[i][kk] = *(const short8*)&Bs[(wn * 64 + i * 16 + lrow) * 64 + lg * 8 + kk * 32];
      }
    __builtin_amdgcn_s_setprio(1);
#pragma unroll
    for (int kk = 0; kk < 2; kk++)
#pragma unroll
      for (int i = 0; i < 4; i++)
#pragma unroll
        for (int j = 0; j < 4; j++)
          acc[i][j] = __builtin_amdgcn_mfma_f32_16x16x32_bf16(af[i][kk], bfr[j][kk], acc[i][j], 0, 0, 0);
    __builtin_amdgcn_s_setprio(0);
  }

  const int rb0 = m0 + wm * 64 + lg * 4;
#pragma unroll
  for (int i = 0; i < 4; i++) {
#pragma unroll
    for (int j = 0; j < 4; j++) {
      int col = n0 + wn * 64 + j * 16 + lrow;
      if (col >= N) continue;
#pragma unroll
      for (int r = 0; r < 4; r++) {
        int row = rb0 + i * 16 + r;
        if (row >= M) continue;
        float v = acc[i][j][r];
        size_t off = (size_t)row * N + col;
        if (EPI == 0) {
          ((short*)Cout)[off] = f2bf(v);
        } else if (EPI == 1) {
          float x = v + bias[col];
          ((short*)Cout)[off] = f2bf(x / (1.f + __expf(-x)));
        } else if (EPI == 2) {
          float g = 1.f / (1.f + __expf(-(v + bias[col])));
          ((short*)Cout)[off] = f2bf(bf2f(x1[off]) + g * bf2f(x2[off]));
        } else {
          ((float*)Cout)[off] = v + bias[col] + bf2f(res[off]);
        }
      }
    }
  }
}

// ---------------------------------------------------------------------------
// 3. V -> V^T with per-64 kv-permutation pi(c) = (c&15)*4 + (c>>4)  [r3 verified]
// ---------------------------------------------------------------------------
__global__ __launch_bounds__(256) void k_build_vt(const short* __restrict__ qkv,
                                                  short* __restrict__ vt) {
  __shared__ __align__(16) short T[128 * 80];
  const int bh = blockIdx.y, st = blockIdx.x;
  const int b = bh >> 3, h = bh & 7;
  const int t = threadIdx.x;
  for (int c = t; c < 1280; c += 256) {
    int r = c / 10, blk = c % 10;
    *(short8*)&T[r * 80 + blk * 8] =
        *(const short8*)(qkv + (size_t)(b * 2048 + st * 128 + r) * 1920 + 1280 + h * 80 + blk * 8);
  }
  __syncthreads();
  for (int c = t; c < 1280; c += 256) {
    int dd = c % 80, qc = (c / 80) * 8;
    short8 v;
#pragma unroll
    for (int i = 0; i < 8; i++) {
      int q = qc + i;
      int tile = q >> 6, p = q & 63;
      int src = (tile << 6) + (p >> 2) + ((p & 3) << 4);  // inv_pi
      v[i] = T[src * 80 + dd];
    }
    *(short8*)(vt + ((size_t)bh * 80 + dd) * 2048 + st * 128 + qc) = v;
  }
}

// ---------------------------------------------------------------------------
// 4. Flash attention: 8 waves x 16 q-rows = 128 q/block; KVBLK=64.
//    r12 math (fixed-shift softmax, deferred sum, f2bf pack) unchanged;
//    only the block shape changed (staging per-thread halves).
// ---------------------------------------------------------------------------
__global__ __launch_bounds__(512) void k_attn(const short* __restrict__ qkv,
                                              const short* __restrict__ vt,
                                              short* __restrict__ outp) {
  __shared__ __align__(16) short Ks[64 * 104];
  __shared__ __align__(16) char Vs[80 * 128];
  __shared__ __align__(16) char Ps[8][2048];

  // 512 blocks, 64/XCD -> 16 consecutive swz share bh (K/V panels, 2.6MB/XCD)
  const int swzb = xcd_swz(blockIdx.x, 512);
  const int qt = swzb & 15, bh = swzb >> 4;
  const int b = bh >> 3, h = bh & 7;
  const int t = threadIdx.x, w = t >> 6, ln = t & 63;
  const int lg = ln >> 4, lr = ln & 15;
  const float sc2 = 0.111803398875f * 1.4426950408889634f;  // scale * log2(e)
  const float SHIFT2 = 32.0f;  // fixed softmax shift (log2 domain)

  short8 qfrag[3];
  {
    const short* qrow = qkv + (size_t)(b * 2048 + qt * 128 + w * 16 + lr) * 1920 + h * 80;
#pragma unroll
    for (int ks = 0; ks < 3; ks++) {
      int off = ks * 32 + lg * 8;
      short8 v = {0, 0, 0, 0, 0, 0, 0, 0};
      if (off < 80) v = *(const short8*)(qrow + off);
      qfrag[ks] = v;
    }
  }

  const short* kbase = qkv + (size_t)b * 2048 * 1920 + 640 + h * 80;
  const short* vbase = vt + (size_t)bh * 80 * 2048;

  // K: 768 chunks (64 rows x 12 slots, pad>=10) over 512 threads: c=t, c=t+512(t<256)
  // V: 640 chunks (80 rows x 8 slots) over 512 threads: c=t(t<640 always), c=t+512(t<128)
  int kr0 = t / 12, kb0 = t % 12;
  int kr1 = (t + 512) / 12, kb1 = (t + 512) % 12;
  int vr0 = t >> 3, vb0 = t & 7;
  int vr1 = (t + 512) >> 3, vb1 = (t + 512) & 7;
  const bool kv1 = (t < 256), vv1 = (t < 128);

  short8 kreg0 = {0,0,0,0,0,0,0,0}, kreg1 = kreg0, vreg0 = kreg0, vreg1 = kreg0;

  if (kb0 < 10) kreg0 = *(const short8*)(kbase + (size_t)kr0 * 1920 + kb0 * 8);
  if (kv1 && kb1 < 10) kreg1 = *(const short8*)(kbase + (size_t)kr1 * 1920 + kb1 * 8);
  vreg0 = *(const short8*)(vbase + (size_t)vr0 * 2048 + vb0 * 8);
  if (vv1) vreg1 = *(const short8*)(vbase + (size_t)vr1 * 2048 + vb1 * 8);

  f32x4 oacc[5];
#pragma unroll
  for (int f = 0; f < 5; f++) oacc[f] = (f32x4){0.f, 0.f, 0.f, 0.f};
  float psacc[4] = {0.f, 0.f, 0.f, 0.f};  // per-lane partial row sums

  for (int kt = 0; kt < 32; kt++) {
    __syncthreads();
    *(short8*)&Ks[kr0 * 104 + kb0 * 8] = kreg0;
    if (kv1) *(short8*)&Ks[kr1 * 104 + kb1 * 8] = kreg1;
    {
      int dst0 = (vr0 * 128 + vb0 * 16) ^ ((vr0 & 7) << 4);
      *(short8*)&Vs[dst0] = vreg0;
      if (vv1) {
        int dst1 = (vr1 * 128 + vb1 * 16) ^ ((vr1 & 7) << 4);
        *(short8*)&Vs[dst1] = vreg1;
      }
    }
    __syncthreads();

    if (kt < 31) {
      const short* kb2 = kbase + (size_t)(kt + 1) * 64 * 1920;
      const short* vb2 = vbase + (size_t)(kt + 1) * 64;
      if (kb0 < 10) kreg0 = *(const short8*)(kb2 + (size_t)kr0 * 1920 + kb0 * 8);
      if (kv1 && kb1 < 10) kreg1 = *(const short8*)(kb2 + (size_t)kr1 * 1920 + kb1 * 8);
      vreg0 = *(const short8*)(vb2 + (size_t)vr0 * 2048 + vb0 * 8);
      if (vv1) vreg1 = *(const short8*)(vb2 + (size_t)vr1 * 2048 + vb1 * 8);
    }

    f32x4 sf[4];
#pragma unroll
    for (int j = 0; j < 4; j++) sf[j] = (f32x4){0.f, 0.f, 0.f, 0.f};
    __builtin_amdgcn_s_setprio(1);
#pragma unroll
    for (int ks = 0; ks < 3; ks++) {
#pragma unroll
      for (int j = 0; j < 4; j++) {
        short8 bk = *(const short8*)&Ks[(j * 16 + lr) * 104 + ks * 32 + lg * 8];
        sf[j] = __builtin_amdgcn_mfma_f32_16x16x32_bf16(qfrag[ks], bk, sf[j], 0, 0, 0);
      }
    }
    __builtin_amdgcn_s_setprio(0);

    // fixed-shift softmax: p = 2^(s*sc2 - SHIFT2)
    char* Pw = Ps[w];
#pragma unroll
    for (int r = 0; r < 4; r++) {
      int row = lg * 4 + r;
      float p0 = exp2f(sf[0][r] * sc2 - SHIFT2);
      float p1 = exp2f(sf[1][r] * sc2 - SHIFT2);
      float p2 = exp2f(sf[2][r] * sc2 - SHIFT2);
      float p3 = exp2f(sf[3][r] * sc2 - SHIFT2);
      psacc[r] += (p0 + p1) + (p2 + p3);
      short4v pk;
      pk[0] = f2bf(p0); pk[1] = f2bf(p1); pk[2] = f2bf(p2); pk[3] = f2bf(p3);
      int addr = (row * 128 + lr * 8) ^ ((row & 7) << 4);
      *(short4v*)&Pw[addr] = pk;
    }

    __builtin_amdgcn_s_setprio(1);
#pragma unroll
    for (int ks = 0; ks < 2; ks++) {
      short8 ap = *(const short8*)&Pw[(lr * 128 + ks * 64 + lg * 16) ^ ((lr & 7) << 4)];
#pragma unroll
      for (int f = 0; f < 5; f++) {
        int vrow = f * 16 + lr;
        short8 bv = *(const short8*)&Vs[(vrow * 128 + ks * 64 + lg * 16) ^ ((vrow & 7) << 4)];
        oacc[f] = __builtin_amdgcn_mfma_f32_16x16x32_bf16(ap, bv, oacc[f], 0, 0, 0);
      }
    }
    __builtin_amdgcn_s_setprio(0);
  }

  // deferred row-sum reduce (once)
  float lrowv[4];
#pragma unroll
  for (int r = 0; r < 4; r++) {
    float sum = psacc[r];
#pragma unroll
    for (int off = 8; off >= 1; off >>= 1) sum += __shfl_xor(sum, off, 64);
    lrowv[r] = sum;
  }

#pragma unroll
  for (int f = 0; f < 5; f++) {
#pragma unroll
    for (int r = 0; r < 4; r++) {
      int q = qt * 128 + w * 16 + lg * 4 + r;
      float o = oacc[f][r] / lrowv[r];
      outp[(size_t)(b * 2048 + q) * 640 + h * 80 + f * 16 + lr] = f2bf(o);
    }
  }
}

// ---------------------------------------------------------------------------
// 5. AU cross-attention (A=16 kv); aukv = [64][1280] (K | V)
// ---------------------------------------------------------------------------
__global__ __launch_bounds__(256) void k_au_attn(const short* __restrict__ qkv,
                                                 const short* __restrict__ aukv,
                                                 const float* __restrict__ temp,
                                                 short* __restrict__ auhs) {
  __shared__ __align__(16) short aK[16 * 640];
  __shared__ __align__(16) short aV[16 * 640];
  const int b = blockIdx.y;
  const int t = threadIdx.x;
  for (int c = t; c < 2560; c += 256) {
    int arr = c / 1280, cc = c - arr * 1280;
    int r = cc / 80, blk = cc % 80;
    const short* s = aukv + (size_t)(b * 16 + r) * 1280 + arr * 640 + blk * 8;
    short* d = (arr ? aV : aK) + r * 640 + blk * 8;
    *(short8*)d = *(const short8*)s;
  }
  __syncthreads();
  const int sl = t & 31, h = t >> 5;
  const int s = blockIdx.x * 32 + sl;
  const float alpha = 0.111803398875f * temp[0];
  const float LOG2E = 1.4426950408889634f;

  float qf[80];
  {
    const short* q = qkv + (size_t)(b * 2048 + s) * 1920 + h * 80;
#pragma unroll
    for (int c = 0; c < 10; c++) {
      short8 v = *(const short8*)(q + c * 8);
#pragma unroll
      for (int j = 0; j < 8; j++) qf[c * 8 + j] = bf2f(v[j]);
    }
  }
  float lgt[16];
#pragma unroll
  for (int a = 0; a < 16; a++) {
    const short* kr = &aK[a * 640 + h * 80];
    float acc = 0.f;
#pragma unroll
    for (int c = 0; c < 10; c++) {
      short8 v = *(const short8*)(kr + c * 8);
#pragma unroll
      for (int j = 0; j < 8; j++) acc += qf[c * 8 + j] * bf2f(v[j]);
    }
    lgt[a] = acc * alpha;
  }
  float m = lgt[0];
#pragma unroll
  for (int a = 1; a < 16; a++) m = fmaxf(m, lgt[a]);
  float se = 0.f;
#pragma unroll
  for (int a = 0; a < 16; a++) { lgt[a] = exp2f((lgt[a] - m) * LOG2E); se += lgt[a]; }
  float inv = 1.f / se;

  float o[80];
#pragma unroll
  for (int i = 0; i < 80; i++) o[i] = 0.f;
#pragma unroll
  for (int a = 0; a < 16; a++) {
    float pa = lgt[a] * inv;
    const short* vr = &aV[a * 640 + h * 80];
#pragma unroll
    for (int c = 0; c < 10; c++) {
      short8 v = *(const short8*)(vr + c * 8);
#pragma unroll
      for (int j = 0; j < 8; j++) o[c * 8 + j] += pa * bf2f(v[j]);
    }
  }
  short* op = auhs + (size_t)(b * 2048 + s) * 640 + h * 80;
#pragma unroll
  for (int c = 0; c < 10; c++) {
    short8 v;
#pragma unroll
    for (int j = 0; j < 8; j++) v[j] = f2bf(o[c * 8 + j]);
    *(short8*)(op + c * 8) = v;
  }
}

// ---------------------------------------------------------------------------
// Orchestration
// ---------------------------------------------------------------------------
extern "C" void kernel_launch(void* const* d_in, const int* in_sizes, int n_in,
                              void* d_out, int out_size, void* d_ws, size_t ws_size,
                              hipStream_t stream) {
  (void)in_sizes; (void)n_in; (void)out_size; (void)ws_size;

  const void* hidden = d_in[0];
  const void* auemb  = d_in[1];

  char* ws = (char*)d_ws;
  int* FLAG   = (int*)(ws + 0);
  float* BG1  = (float*)(ws + 1024);
  float* BG2  = (float*)(ws + 4096);
  float* BOUT = (float*)(ws + 8192);
  float* TEMP = (float*)(ws + 12288);

  size_t o = 16384;
  short* HSB = (short*)(ws + o);    o += 10485760;  // [8192][640]
  short* AUB = (short*)(ws + o);    o += 98304;     // [64][768]
  short* WQKVT = (short*)(ws + o);  o += 2457600;   // [1920][640]
  short* WAKVT = (short*)(ws + o);  o += 1966080;   // [1280][768]
  short* WG1T = (short*)(ws + o);   o += 409600;    // [320][640]
  short* WG2T = (short*)(ws + o);   o += 409600;    // [640][320]
  short* WOUTT = (short*)(ws + o);  o += 819200;    // [640][640]
  short* QKV = (short*)(ws + o);    o += 31457280;  // [8192][1920]
  short* VT = (short*)(ws + o);     o += 10485760;  // [32][80][2048] pi-permuted
  short* AUKV = (short*)(ws + o);   o += 163840;    // [64][1280]
  short* HSATTN = (short*)(ws + o); o += 10485760;  // [8192][640]
  short* AUHS = (short*)(ws + o);   o += 10485760;  // [8192][640]
  short* G1 = QKV;                                   // reuse: [8192][320]
  short* HSMIX = QKV + 5242880;                      // reuse: [8192][640]

  k_detect<<<1, 256, 0, stream>>>((const uint32_t*)hidden, FLAG);

  k_conv_vec<<<5168, 256, 0, stream>>>(hidden, HSB, 1310720, auemb, AUB, 12288, FLAG);

  WTable tb;
  tb.d[0] = { d_in[2],  WQKVT,              640, 640, 640, 0    };  // w_q
  tb.d[1] = { d_in[3],  WQKVT + 409600,     640, 640, 640, 400  };  // w_k
  tb.d[2] = { d_in[4],  WQKVT + 819200,     640, 640, 640, 800  };  // w_v
  tb.d[3] = { d_in[5],  WAKVT,              768, 640, 768, 1200 };  // w_ak
  tb.d[4] = { d_in[6],  WAKVT + 640 * 768,  768, 640, 768, 1680 };  // w_av
  tb.d[5] = { d_in[7],  WG1T,               640, 320, 640, 2160 };  // w_g1
  tb.d[6] = { d_in[9],  WG2T,               320, 640, 320, 2360 };  // w_g2
  tb.d[7] = { d_in[11], WOUTT,              640, 640, 640, 2560 };  // w_out
  k_conv_w<<<2960, dim3(32, 8), 0, stream>>>(tb, FLAG);
  k_conv_bias<<<7, 256, 0, stream>>>(d_in[8], d_in[10], d_in[12], d_in[13],
                                     BG1, BG2, BOUT, TEMP, FLAG);

  // QKV projection: [8192,640] @ [640,1920]  (1D grid, XCD-chunked)
  k_gemm_bt<0><<<960, 256, 0, stream>>>(HSB, WQKVT, QKV, 8192, 1920, 640, 15,
                                        nullptr, nullptr, nullptr, nullptr);
  // au_k | au_v fused: [64,768] @ [768,1280]
  k_gemm_bt<0><<<10, 256, 0, stream>>>(AUB, WAKVT, AUKV, 64, 1280, 768, 10,
                                       nullptr, nullptr, nullptr, nullptr);

  k_build_vt<<<dim3(16, 32), 256, 0, stream>>>(QKV, VT);
  k_attn<<<512, 512, 0, stream>>>(QKV, VT, HSATTN);
  k_au_attn<<<dim3(64, 4), 256, 0, stream>>>(QKV, AUKV, TEMP, AUHS);

  // gate MLP
  k_gemm_bt<1><<<192, 256, 0, stream>>>(AUHS, WG1T, G1, 8192, 320, 640, 3,
                                        BG1, nullptr, nullptr, nullptr);
  k_gemm_bt<2><<<320, 256, 0, stream>>>(G1, WG2T, HSMIX, 8192, 640, 320, 5,
                                        BG2, HSATTN, AUHS, nullptr);
  // final out (float32)
  k_gemm_bt<3><<<320, 256, 0, stream>>>(HSMIX, WOUTT, d_out, 8192, 640, 640, 5,
                                        BOUT, nullptr, nullptr, HSB);
}

// Round 15
// 308.540 us; speedup vs baseline: 1.2587x; 1.1168x over previous
//
#include <hip/hip_runtime.h>
#include <stdint.h>

typedef __attribute__((ext_vector_type(8))) short short8;    // 8 bf16 = 16B
typedef __attribute__((ext_vector_type(4))) short short4v;
typedef __attribute__((ext_vector_type(4))) float f32x4;
typedef __attribute__((ext_vector_type(2))) uint32_t u32x2;

#define DEV static __device__ __forceinline__

DEV short f2bf(float f) {
  union { float f; uint32_t u; } v; v.f = f;
  uint32_t r = (v.u + 0x7fffu + ((v.u >> 16) & 1u)) >> 16;
  return (short)(uint16_t)r;
}
DEV float bf2f(short s) {
  union { uint32_t u; float f; } v; v.u = ((uint32_t)(uint16_t)s) << 16;
  return v.f;
}
DEV uint32_t fbits(float f) { union { float f; uint32_t u; } v; v.f = f; return v.u; }
DEV int imin(int a, int b) { return a < b ? a : b; }
// bijective XCD chunking (m204)
DEV int xcd_swz(int bid, int nwg) {
  int q8 = nwg >> 3, r8 = nwg & 7;
  int xcd = bid & 7, lin = bid >> 3;
  return (xcd < r8 ? xcd * (q8 + 1) : r8 * (q8 + 1) + (xcd - r8) * q8) + lin;
}
// per-block dtype detect (deterministic; every block computes the same answer)
DEV int detect_flag(const uint32_t* src, int t) {
  __shared__ int cnt;
  if (t == 0) cnt = 0;
  __syncthreads();
  uint32_t u = src[t & 255];
  int e = (int)((u >> 7) & 0xffu);
  if (e >= 110 && e <= 135) atomicAdd(&cnt, 1);
  __syncthreads();
  return cnt > 128;
}

// B=4, S=2048, D=640, H=8, d=80, C=768, A=16

struct WDesc { const void* src; short* dst; int K, N, dstride, tile0; };
struct WTable { WDesc d[8]; };

// ---------------------------------------------------------------------------
// 1. k_prep: dtype detect (per-block) + conv_vec + conv_w + conv_bias fused.
//    blocks [0,5168): vec; [5168,8128): weights; [8128,8135): biases.
// ---------------------------------------------------------------------------
__global__ __launch_bounds__(256) void k_prep(
    const void* __restrict__ hidden, const void* __restrict__ auemb,
    short* __restrict__ HSB, short* __restrict__ AUB, WTable tb,
    const void* b1, const void* b2, const void* b3, const void* tp,
    float* B1, float* B2, float* B3, float* T) {
  const int t = threadIdx.x;
  const int isbf = detect_flag((const uint32_t*)hidden, t);
  const int bid = blockIdx.x;

  if (bid < 5168) {
    // vector convert: hidden (n1=1310720 groups) then au_emb (n2=12288)
    int i = bid * 256 + t;
    const void* src; short* dst;
    if (i < 1310720) { src = hidden; dst = HSB; }
    else { src = auemb; dst = AUB; i -= 1310720; }
    if (isbf) {
      ((short4v*)dst)[i] = ((const short4v*)src)[i];
    } else {
      f32x4 v = ((const f32x4*)src)[i];
      short4v o;
      o[0] = f2bf(v[0]); o[1] = f2bf(v[1]); o[2] = f2bf(v[2]); o[3] = f2bf(v[3]);
      ((short4v*)dst)[i] = o;
    }
  } else if (bid < 8128) {
    // weight transpose+convert
    __shared__ float tile[32][33];
    int tid = bid - 5168;
    int idx = 0;
#pragma unroll
    for (int i = 1; i < 8; i++) if (tid >= tb.d[i].tile0) idx = i;
    WDesc wd = tb.d[idx];
    int local = tid - wd.tile0;
    int ntiles = wd.N >> 5;
    int n0 = (local % ntiles) * 32, k0 = (local / ntiles) * 32;
    int tx = t & 31, ty = t >> 5;  // flattened 32 x 8
#pragma unroll
    for (int i = 0; i < 4; i++) {
      int r = k0 + ty + i * 8, c = n0 + tx;
      float v = 0.f;
      if (r < wd.K && c < wd.N)
        v = isbf ? bf2f(((const short*)wd.src)[(size_t)r * wd.N + c])
                 : ((const float*)wd.src)[(size_t)r * wd.N + c];
      tile[ty + i * 8][tx] = v;
    }
    __syncthreads();
#pragma unroll
    for (int i = 0; i < 4; i++) {
      int n = n0 + ty + i * 8, k = k0 + tx;
      if (n < wd.N && k < wd.K) wd.dst[(size_t)n * wd.dstride + k] = f2bf(tile[tx][ty + i * 8]);
    }
  } else {
    int i = (bid - 8128) * 256 + t;
    const void* s; float* d; int j;
    if (i < 320) { s = b1; d = B1; j = i; }
    else if (i < 960) { s = b2; d = B2; j = i - 320; }
    else if (i < 1600) { s = b3; d = B3; j = i - 960; }
    else if (i == 1600) { s = tp; d = T; j = 0; }
    else return;
    d[j] = isbf ? bf2f(((const short*)s)[j]) : ((const float*)s)[j];
  }
}

// ---------------------------------------------------------------------------
// 2. GEMM core: 128x128 tile, BK=64, global_load_lds width-16
// ---------------------------------------------------------------------------
template <int EPI>
DEV void gemm_core(const short* __restrict__ A, const short* __restrict__ Wt,
                   void* __restrict__ Cout, int M, int N, int K, int m0, int n0,
                   const float* __restrict__ bias, const short* __restrict__ x1,
                   const short* __restrict__ x2, const short* __restrict__ res) {
  __shared__ __align__(16) short As[128 * 64];
  __shared__ __align__(16) short Bs[128 * 64];
  const int t = threadIdx.x;
  const int w = t >> 6, ln = t & 63;
  const int wm = w >> 1, wn = w & 1;
  const int lrow = ln & 15, lg = ln >> 4;

  f32x4 acc[4][4];
#pragma unroll
  for (int i = 0; i < 4; i++)
#pragma unroll
    for (int j = 0; j < 4; j++) acc[i][j] = (f32x4){0.f, 0.f, 0.f, 0.f};

  for (int k0 = 0; k0 < K; k0 += 64) {
    __syncthreads();
#pragma unroll
    for (int c = 0; c < 4; c++) {
      int cc = c * 256 + t;
      int r = cc >> 3, col = (cc & 7) * 8;
      int ra = imin(m0 + r, M - 1);
      int rb = imin(n0 + r, N - 1);
      __builtin_amdgcn_global_load_lds(
          (const __attribute__((address_space(1))) void*)(A + (size_t)ra * K + k0 + col),
          (__attribute__((address_space(3))) void*)&As[(c * 256 + w * 64) * 8],
          16, 0, 0);
      __builtin_amdgcn_global_load_lds(
          (const __attribute__((address_space(1))) void*)(Wt + (size_t)rb * K + k0 + col),
          (__attribute__((address_space(3))) void*)&Bs[(c * 256 + w * 64) * 8],
          16, 0, 0);
    }
    __syncthreads();
    short8 af[4][2], bfr[4][2];
#pragma unroll
    for (int i = 0; i < 4; i++)
#pragma unroll
      for (int kk = 0; kk < 2; kk++) {
        af[i][kk] = *(const short8*)&As[(wm * 64 + i * 16 + lrow) * 64 + lg * 8 + kk * 32];
        bfr[i][kk] = *(const short8*)&Bs[(wn * 64 + i * 16 + lrow) * 64 + lg * 8 + kk * 32];
      }
    __builtin_amdgcn_s_setprio(1);
#pragma unroll
    for (int kk = 0; kk < 2; kk++)
#pragma unroll
      for (int i = 0; i < 4; i++)
#pragma unroll
        for (int j = 0; j < 4; j++)
          acc[i][j] = __builtin_amdgcn_mfma_f32_16x16x32_bf16(af[i][kk], bfr[j][kk], acc[i][j], 0, 0, 0);
    __builtin_amdgcn_s_setprio(0);
  }

  const int rb0 = m0 + wm * 64 + lg * 4;
#pragma unroll
  for (int i = 0; i < 4; i++) {
#pragma unroll
    for (int j = 0; j < 4; j++) {
      int col = n0 + wn * 64 + j * 16 + lrow;
      if (col >= N) continue;
#pragma unroll
      for (int r = 0; r < 4; r++) {
        int row = rb0 + i * 16 + r;
        if (row >= M) continue;
        float v = acc[i][j][r];
        size_t off = (size_t)row * N + col;
        if (EPI == 0) {
          ((short*)Cout)[off] = f2bf(v);
        } else if (EPI == 1) {
          float x = v + bias[col];
          ((short*)Cout)[off] = f2bf(x / (1.f + __expf(-x)));
        } else if (EPI == 2) {
          float g = 1.f / (1.f + __expf(-(v + bias[col])));
          ((short*)Cout)[off] = f2bf(bf2f(x1[off]) + g * bf2f(x2[off]));
        } else {
          ((float*)Cout)[off] = v + bias[col] + bf2f(res[off]);
        }
      }
    }
  }
}

template <int EPI>
__global__ __launch_bounds__(256) void k_gemm_bt(
    const short* __restrict__ A, const short* __restrict__ Wt, void* __restrict__ Cout,
    int M, int N, int K, int nbx,
    const float* __restrict__ bias, const short* __restrict__ x1,
    const short* __restrict__ x2, const short* __restrict__ res) {
  const int swz = xcd_swz(blockIdx.x, gridDim.x);
  gemm_core<EPI>(A, Wt, Cout, M, N, K, (swz / nbx) * 128, (swz % nbx) * 128,
                 bias, x1, x2, res);
}

// QKV projection (960 blocks, XCD-chunked) + AU-KV GEMM (10 blocks), one launch
__global__ __launch_bounds__(256) void k_gemm_fused(
    const short* __restrict__ A0, const short* __restrict__ W0, short* __restrict__ C0,
    const short* __restrict__ A1, const short* __restrict__ W1, short* __restrict__ C1) {
  const int bid = blockIdx.x;
  if (bid < 960) {
    int swz = xcd_swz(bid, 960);
    gemm_core<0>(A0, W0, C0, 8192, 1920, 640, (swz / 15) * 128, (swz % 15) * 128,
                 nullptr, nullptr, nullptr, nullptr);
  } else {
    int local = bid - 960;
    gemm_core<0>(A1, W1, C1, 64, 1280, 768, 0, local * 128,
                 nullptr, nullptr, nullptr, nullptr);
  }
}

// ---------------------------------------------------------------------------
// 3. k_vt_au: build_vt (blocks 0..511) + AU cross-attention (512..767) fused
// ---------------------------------------------------------------------------
__global__ __launch_bounds__(256) void k_vt_au(const short* __restrict__ qkv,
                                               short* __restrict__ vt,
                                               const short* __restrict__ aukv,
                                               const float* __restrict__ temp,
                                               short* __restrict__ auhs) {
  __shared__ __align__(16) short SH[20480];  // 40 KB shared by both branches
  const int bid = blockIdx.x;
  const int t = threadIdx.x;

  if (bid < 512) {
    // V -> V^T with per-64 kv-permutation pi(c)=(c&15)*4+(c>>4)  [r3 verified]
    short* T = SH;  // [128][80]
    const int st = bid & 15, bh = bid >> 4;
    const int b = bh >> 3, h = bh & 7;
    for (int c = t; c < 1280; c += 256) {
      int r = c / 10, blk = c % 10;
      *(short8*)&T[r * 80 + blk * 8] =
          *(const short8*)(qkv + (size_t)(b * 2048 + st * 128 + r) * 1920 + 1280 + h * 80 + blk * 8);
    }
    __syncthreads();
    for (int c = t; c < 1280; c += 256) {
      int dd = c % 80, qc = (c / 80) * 8;
      short8 v;
#pragma unroll
      for (int i = 0; i < 8; i++) {
        int q = qc + i;
        int tile = q >> 6, p = q & 63;
        int src = (tile << 6) + (p >> 2) + ((p & 3) << 4);  // inv_pi
        v[i] = T[src * 80 + dd];
      }
      *(short8*)(vt + ((size_t)bh * 80 + dd) * 2048 + st * 128 + qc) = v;
    }
  } else {
    // AU cross-attention (A=16 kv)
    short* aK = SH;            // [16][640]
    short* aV = SH + 16 * 640; // [16][640]
    const int bid2 = bid - 512;
    const int sx = bid2 & 63, b = bid2 >> 6;
    for (int c = t; c < 2560; c += 256) {
      int arr = c / 1280, cc = c - arr * 1280;
      int r = cc / 80, blk = cc % 80;
      const short* s = aukv + (size_t)(b * 16 + r) * 1280 + arr * 640 + blk * 8;
      short* d = (arr ? aV : aK) + r * 640 + blk * 8;
      *(short8*)d = *(const short8*)s;
    }
    __syncthreads();
    const int sl = t & 31, h = t >> 5;
    const int s = sx * 32 + sl;
    const float alpha = 0.111803398875f * temp[0];
    const float LOG2E = 1.4426950408889634f;

    float qf[80];
    {
      const short* q = qkv + (size_t)(b * 2048 + s) * 1920 + h * 80;
#pragma unroll
      for (int c = 0; c < 10; c++) {
        short8 v = *(const short8*)(q + c * 8);
#pragma unroll
        for (int j = 0; j < 8; j++) qf[c * 8 + j] = bf2f(v[j]);
      }
    }
    float lgt[16];
#pragma unroll
    for (int a = 0; a < 16; a++) {
      const short* kr = &aK[a * 640 + h * 80];
      float acc = 0.f;
#pragma unroll
      for (int c = 0; c < 10; c++) {
        short8 v = *(const short8*)(kr + c * 8);
#pragma unroll
        for (int j = 0; j < 8; j++) acc += qf[c * 8 + j] * bf2f(v[j]);
      }
      lgt[a] = acc * alpha;
    }
    float m = lgt[0];
#pragma unroll
    for (int a = 1; a < 16; a++) m = fmaxf(m, lgt[a]);
    float se = 0.f;
#pragma unroll
    for (int a = 0; a < 16; a++) { lgt[a] = exp2f((lgt[a] - m) * LOG2E); se += lgt[a]; }
    float inv = 1.f / se;

    float o[80];
#pragma unroll
    for (int i = 0; i < 80; i++) o[i] = 0.f;
#pragma unroll
    for (int a = 0; a < 16; a++) {
      float pa = lgt[a] * inv;
      const short* vr = &aV[a * 640 + h * 80];
#pragma unroll
      for (int c = 0; c < 10; c++) {
        short8 v = *(const short8*)(vr + c * 8);
#pragma unroll
        for (int j = 0; j < 8; j++) o[c * 8 + j] += pa * bf2f(v[j]);
      }
    }
    short* op = auhs + (size_t)(b * 2048 + s) * 640 + h * 80;
#pragma unroll
    for (int c = 0; c < 10; c++) {
      short8 v;
#pragma unroll
      for (int j = 0; j < 8; j++) v[j] = f2bf(o[c * 8 + j]);
      *(short8*)(op + c * 8) = v;
    }
  }
}

// ---------------------------------------------------------------------------
// 4. Flash attention: 8 waves x 16 q-rows; fixed-shift softmax; trunc P-pack
// ---------------------------------------------------------------------------
__global__ __launch_bounds__(512) void k_attn(const short* __restrict__ qkv,
                                              const short* __restrict__ vt,
                                              short* __restrict__ outp) {
  __shared__ __align__(16) short Ks[64 * 104];
  __shared__ __align__(16) char Vs[80 * 128];
  __shared__ __align__(16) char Ps[8][2048];

  const int swzb = xcd_swz(blockIdx.x, 512);
  const int qt = swzb & 15, bh = swzb >> 4;
  const int b = bh >> 3, h = bh & 7;
  const int t = threadIdx.x, w = t >> 6, ln = t & 63;
  const int lg = ln >> 4, lr = ln & 15;
  const float sc2 = 0.111803398875f * 1.4426950408889634f;  // scale * log2(e)
  const float SHIFT2 = 32.0f;

  short8 qfrag[3];
  {
    const short* qrow = qkv + (size_t)(b * 2048 + qt * 128 + w * 16 + lr) * 1920 + h * 80;
#pragma unroll
    for (int ks = 0; ks < 3; ks++) {
      int off = ks * 32 + lg * 8;
      short8 v = {0, 0, 0, 0, 0, 0, 0, 0};
      if (off < 80) v = *(const short8*)(qrow + off);
      qfrag[ks] = v;
    }
  }

  const short* kbase = qkv + (size_t)b * 2048 * 1920 + 640 + h * 80;
  const short* vbase = vt + (size_t)bh * 80 * 2048;

  int kr0 = t / 12, kb0 = t % 12;
  int kr1 = (t + 512) / 12, kb1 = (t + 512) % 12;
  int vr0 = t >> 3, vb0 = t & 7;
  int vr1 = (t + 512) >> 3, vb1 = (t + 512) & 7;
  const bool kv1 = (t < 256), vv1 = (t < 128);

  short8 kreg0 = {0,0,0,0,0,0,0,0}, kreg1 = kreg0, vreg0 = kreg0, vreg1 = kreg0;

  if (kb0 < 10) kreg0 = *(const short8*)(kbase + (size_t)kr0 * 1920 + kb0 * 8);
  if (kv1 && kb1 < 10) kreg1 = *(const short8*)(kbase + (size_t)kr1 * 1920 + kb1 * 8);
  vreg0 = *(const short8*)(vbase + (size_t)vr0 * 2048 + vb0 * 8);
  if (vv1) vreg1 = *(const short8*)(vbase + (size_t)vr1 * 2048 + vb1 * 8);

  f32x4 oacc[5];
#pragma unroll
  for (int f = 0; f < 5; f++) oacc[f] = (f32x4){0.f, 0.f, 0.f, 0.f};
  float psacc[4] = {0.f, 0.f, 0.f, 0.f};

  for (int kt = 0; kt < 32; kt++) {
    __syncthreads();
    *(short8*)&Ks[kr0 * 104 + kb0 * 8] = kreg0;
    if (kv1) *(short8*)&Ks[kr1 * 104 + kb1 * 8] = kreg1;
    {
      int dst0 = (vr0 * 128 + vb0 * 16) ^ ((vr0 & 7) << 4);
      *(short8*)&Vs[dst0] = vreg0;
      if (vv1) {
        int dst1 = (vr1 * 128 + vb1 * 16) ^ ((vr1 & 7) << 4);
        *(short8*)&Vs[dst1] = vreg1;
      }
    }
    __syncthreads();

    if (kt < 31) {
      const short* kb2 = kbase + (size_t)(kt + 1) * 64 * 1920;
      const short* vb2 = vbase + (size_t)(kt + 1) * 64;
      if (kb0 < 10) kreg0 = *(const short8*)(kb2 + (size_t)kr0 * 1920 + kb0 * 8);
      if (kv1 && kb1 < 10) kreg1 = *(const short8*)(kb2 + (size_t)kr1 * 1920 + kb1 * 8);
      vreg0 = *(const short8*)(vb2 + (size_t)vr0 * 2048 + vb0 * 8);
      if (vv1) vreg1 = *(const short8*)(vb2 + (size_t)vr1 * 2048 + vb1 * 8);
    }

    f32x4 sf[4];
#pragma unroll
    for (int j = 0; j < 4; j++) sf[j] = (f32x4){0.f, 0.f, 0.f, 0.f};
    __builtin_amdgcn_s_setprio(1);
#pragma unroll
    for (int ks = 0; ks < 3; ks++) {
#pragma unroll
      for (int j = 0; j < 4; j++) {
        short8 bk = *(const short8*)&Ks[(j * 16 + lr) * 104 + ks * 32 + lg * 8];
        sf[j] = __builtin_amdgcn_mfma_f32_16x16x32_bf16(qfrag[ks], bk, sf[j], 0, 0, 0);
      }
    }
    __builtin_amdgcn_s_setprio(0);

    // fixed-shift softmax; P packed by truncation (bit ops only)
    char* Pw = Ps[w];
#pragma unroll
    for (int r = 0; r < 4; r++) {
      int row = lg * 4 + r;
      float p0 = exp2f(sf[0][r] * sc2 - SHIFT2);
      float p1 = exp2f(sf[1][r] * sc2 - SHIFT2);
      float p2 = exp2f(sf[2][r] * sc2 - SHIFT2);
      float p3 = exp2f(sf[3][r] * sc2 - SHIFT2);
      psacc[r] += (p0 + p1) + (p2 + p3);
      u32x2 pk;
      pk[0] = (fbits(p0) >> 16) | (fbits(p1) & 0xffff0000u);
      pk[1] = (fbits(p2) >> 16) | (fbits(p3) & 0xffff0000u);
      int addr = (row * 128 + lr * 8) ^ ((row & 7) << 4);
      *(u32x2*)&Pw[addr] = pk;
    }

    __builtin_amdgcn_s_setprio(1);
#pragma unroll
    for (int ks = 0; ks < 2; ks++) {
      short8 ap = *(const short8*)&Pw[(lr * 128 + ks * 64 + lg * 16) ^ ((lr & 7) << 4)];
#pragma unroll
      for (int f = 0; f < 5; f++) {
        int vrow = f * 16 + lr;
        short8 bv = *(const short8*)&Vs[(vrow * 128 + ks * 64 + lg * 16) ^ ((vrow & 7) << 4)];
        oacc[f] = __builtin_amdgcn_mfma_f32_16x16x32_bf16(ap, bv, oacc[f], 0, 0, 0);
      }
    }
    __builtin_amdgcn_s_setprio(0);
  }

  float lrowv[4];
#pragma unroll
  for (int r = 0; r < 4; r++) {
    float sum = psacc[r];
#pragma unroll
    for (int off = 8; off >= 1; off >>= 1) sum += __shfl_xor(sum, off, 64);
    lrowv[r] = sum;
  }

#pragma unroll
  for (int f = 0; f < 5; f++) {
#pragma unroll
    for (int r = 0; r < 4; r++) {
      int q = qt * 128 + w * 16 + lg * 4 + r;
      float o = oacc[f][r] / lrowv[r];
      outp[(size_t)(b * 2048 + q) * 640 + h * 80 + f * 16 + lr] = f2bf(o);
    }
  }
}

// ---------------------------------------------------------------------------
// Orchestration (7 launches)
// ---------------------------------------------------------------------------
extern "C" void kernel_launch(void* const* d_in, const int* in_sizes, int n_in,
                              void* d_out, int out_size, void* d_ws, size_t ws_size,
                              hipStream_t stream) {
  (void)in_sizes; (void)n_in; (void)out_size; (void)ws_size;

  const void* hidden = d_in[0];
  const void* auemb  = d_in[1];

  char* ws = (char*)d_ws;
  float* BG1  = (float*)(ws + 1024);
  float* BG2  = (float*)(ws + 4096);
  float* BOUT = (float*)(ws + 8192);
  float* TEMP = (float*)(ws + 12288);

  size_t o = 16384;
  short* HSB = (short*)(ws + o);    o += 10485760;  // [8192][640]
  short* AUB = (short*)(ws + o);    o += 98304;     // [64][768]
  short* WQKVT = (short*)(ws + o);  o += 2457600;   // [1920][640]
  short* WAKVT = (short*)(ws + o);  o += 1966080;   // [1280][768]
  short* WG1T = (short*)(ws + o);   o += 409600;    // [320][640]
  short* WG2T = (short*)(ws + o);   o += 409600;    // [640][320]
  short* WOUTT = (short*)(ws + o);  o += 819200;    // [640][640]
  short* QKV = (short*)(ws + o);    o += 31457280;  // [8192][1920]
  short* VT = (short*)(ws + o);     o += 10485760;  // [32][80][2048] pi-permuted
  short* AUKV = (short*)(ws + o);   o += 163840;    // [64][1280]
  short* HSATTN = (short*)(ws + o); o += 10485760;  // [8192][640]
  short* AUHS = (short*)(ws + o);   o += 10485760;  // [8192][640]
  short* G1 = QKV;                                   // reuse: [8192][320]
  short* HSMIX = QKV + 5242880;                      // reuse: [8192][640]

  WTable tb;
  tb.d[0] = { d_in[2],  WQKVT,              640, 640, 640, 0    };  // w_q
  tb.d[1] = { d_in[3],  WQKVT + 409600,     640, 640, 640, 400  };  // w_k
  tb.d[2] = { d_in[4],  WQKVT + 819200,     640, 640, 640, 800  };  // w_v
  tb.d[3] = { d_in[5],  WAKVT,              768, 640, 768, 1200 };  // w_ak
  tb.d[4] = { d_in[6],  WAKVT + 640 * 768,  768, 640, 768, 1680 };  // w_av
  tb.d[5] = { d_in[7],  WG1T,               640, 320, 640, 2160 };  // w_g1
  tb.d[6] = { d_in[9],  WG2T,               320, 640, 320, 2360 };  // w_g2
  tb.d[7] = { d_in[11], WOUTT,              640, 640, 640, 2560 };  // w_out

  // 1: all converters (dtype flag computed per-block)
  k_prep<<<8135, 256, 0, stream>>>(hidden, auemb, HSB, AUB, tb,
                                   d_in[8], d_in[10], d_in[12], d_in[13],
                                   BG1, BG2, BOUT, TEMP);
  // 2: QKV projection + AU-KV GEMM
  k_gemm_fused<<<970, 256, 0, stream>>>(HSB, WQKVT, QKV, AUB, WAKVT, AUKV);
  // 3: V^T build + AU cross-attention (independent, overlapped)
  k_vt_au<<<768, 256, 0, stream>>>(QKV, VT, AUKV, TEMP, AUHS);
  // 4: main attention
  k_attn<<<512, 512, 0, stream>>>(QKV, VT, HSATTN);
  // 5-7: gate MLP + output projection
  k_gemm_bt<1><<<192, 256, 0, stream>>>(AUHS, WG1T, G1, 8192, 320, 640, 3,
                                        BG1, nullptr, nullptr, nullptr);
  k_gemm_bt<2><<<320, 256, 0, stream>>>(G1, WG2T, HSMIX, 8192, 640, 320, 5,
                                        BG2, HSATTN, AUHS, nullptr);
  k_gemm_bt<3><<<320, 256, 0, stream>>>(HSMIX, WOUTT, d_out, 8192, 640, 640, 5,
                                        BOUT, nullptr, nullptr, HSB);
}